// Round 11
// baseline (432.998 us; speedup 1.0000x reference)
//
#include <hip/hip_runtime.h>
#include <math.h>

#define FEAT 120
#define HCNT 4

typedef unsigned short ushort_t;
typedef unsigned int uint_t;
typedef __attribute__((ext_vector_type(8))) short short8;
typedef __attribute__((ext_vector_type(4))) float floatx4;

__device__ __forceinline__ float nact_scale(float sumsq) {
    float n = sqrtf(sumsq + 1e-10f);
    float sig = 1.0f / (1.0f + expf(-n));
    return sig / n;
}

__device__ __forceinline__ ushort_t bf16r(float f) {
    uint_t u = __float_as_uint(f);
    u += 0x7fff + ((u >> 16) & 1);   // round-to-nearest-even
    return (ushort_t)(u >> 16);
}

__device__ __forceinline__ uint_t pack2(float lo, float hi) {
    return (uint_t)bf16r(lo) | ((uint_t)bf16r(hi) << 16);
}

#define INV_S32 0.17677669529663687f   // 1/sqrt(32)
#define INV_S16 0.25f                  // 1/sqrt(16)
#define INV_S8  0.35355339059327373f   // 1/sqrt(8)
// tp_dot scales: 1/(sqrt(2l+1)*sqrt(fan)), fan = 32*32 + 16*16*3 + 8*8*5 = 2112
#define S_IR0 0.02175970668223486f
#define S_IR1 0.012562972567021898f
#define S_IR2 0.009731317442393031f

// ---------------- counting sort by dst ----------------

__global__ __launch_bounds__(256) void hist_kernel(const int* __restrict__ dst,
                                                   int* __restrict__ cnt, int E) {
    int e = blockIdx.x * 256 + threadIdx.x;
    if (e < E) atomicAdd(&cnt[dst[e]], 1);
}

__global__ __launch_bounds__(256) void scan_block_kernel(const int* __restrict__ cnt,
                                                         int* __restrict__ excl,
                                                         int* __restrict__ bsum, int n) {
    __shared__ int s[256];
    int t = threadIdx.x;
    int i = blockIdx.x * 256 + t;
    int v = (i < n) ? cnt[i] : 0;
    s[t] = v;
    __syncthreads();
    for (int off = 1; off < 256; off <<= 1) {
        int add = (t >= off) ? s[t - off] : 0;
        __syncthreads();
        s[t] += add;
        __syncthreads();
    }
    if (i < n) excl[i] = s[t] - v;
    if (t == 255) bsum[blockIdx.x] = s[255];
}

__global__ __launch_bounds__(256) void scan_sums_kernel(int* __restrict__ bsum, int nb) {
    __shared__ int s[256];
    int t = threadIdx.x;
    int v = (t < nb) ? bsum[t] : 0;
    s[t] = v;
    __syncthreads();
    for (int off = 1; off < 256; off <<= 1) {
        int add = (t >= off) ? s[t - off] : 0;
        __syncthreads();
        s[t] += add;
        __syncthreads();
    }
    if (t < nb) bsum[t] = s[t] - v;
}

__global__ __launch_bounds__(256) void add_offsets_kernel(int* __restrict__ offsets,
                                                          const int* __restrict__ bsum,
                                                          int* __restrict__ cursor,
                                                          int n, int E) {
    int i = blockIdx.x * 256 + threadIdx.x;
    if (i < n) {
        int off = offsets[i] + bsum[i >> 8];
        offsets[i] = off;
        cursor[i] = off;
    }
    if (i == 0) offsets[n] = E;
}

__global__ __launch_bounds__(256) void scatter_kernel(const int* __restrict__ dst,
                                                      const int* __restrict__ src,
                                                      int* __restrict__ cursor,
                                                      int* __restrict__ ssrc, int E) {
    int e = blockIdx.x * 256 + threadIdx.x;
    if (e < E) {
        int pos = atomicAdd(&cursor[dst[e]], 1);
        ssrc[pos] = src[e];
    }
}

// ---------------- weight prep (zero + fill fused, one block) ----------------

__global__ __launch_bounds__(256) void prep_fill_kernel(
    const float* __restrict__ Wq0, const float* __restrict__ Wq1, const float* __restrict__ Wq2,
    const float* __restrict__ Wk0, const float* __restrict__ Wk1, const float* __restrict__ Wk2,
    const float* __restrict__ Wv0, const float* __restrict__ Wv1, const float* __restrict__ Wv2,
    const float* __restrict__ Wd0, const float* __restrict__ Wd1, const float* __restrict__ Wd2,
    float* __restrict__ wt, ushort_t* __restrict__ wdtb)
{
    int t = threadIdx.x;
    for (int it = t; it < 32768; it += 256) ((uint_t*)wdtb)[it] = 0;
    __syncthreads();
    for (int it = t; it < 3072; it += 256) {
        int p = it >> 10, rem = it & 1023, o = rem >> 5, i = rem & 31;
        const float* W = (p == 0) ? Wq0 : (p == 1) ? Wk0 : Wv0;
        wt[p * 1344 + o * 32 + i] = W[i * 32 + o] * INV_S32;
    }
    for (int it = t; it < 768; it += 256) {
        int p = it >> 8, rem = it & 255, o = rem >> 4, i = rem & 15;
        const float* W = (p == 0) ? Wq1 : (p == 1) ? Wk1 : Wv1;
        wt[p * 1344 + 1024 + o * 16 + i] = W[i * 16 + o] * INV_S16;
    }
    for (int it = t; it < 192; it += 256) {
        int p = it / 64, rem = it % 64, o = rem >> 3, i = rem & 7;
        const float* W = (p == 0) ? Wq2 : (p == 1) ? Wk2 : Wv2;
        wt[p * 1344 + 1280 + o * 8 + i] = W[i * 8 + o] * INV_S8;
    }
    // wd l=0: Wd0 (32,32,4): Wd0[i][j][h] = Wd0[i*128 + j*4 + h]
    for (int it = t; it < 4096; it += 256) {
        int i = it / 128, rem = it % 128, j = rem / 4, h = rem % 4;
        wdtb[(h * 128 + j) * 128 + i] = bf16r(Wd0[i * 128 + j * 4 + h] * S_IR0);
    }
    // wd l=1: Wd1 (16,16,4)
    for (int it = t; it < 3072; it += 256) {
        int i = it / 192, rem = it % 192, j = rem / 12, r2 = rem % 12, c = r2 / 4, h = r2 % 4;
        wdtb[(h * 128 + 32 + j * 3 + c) * 128 + (32 + i * 3 + c)] = bf16r(Wd1[i * 64 + j * 4 + h] * S_IR1);
    }
    // wd l=2: Wd2 (8,8,4)
    for (int it = t; it < 1280; it += 256) {
        int i = it / 160, rem = it % 160, j = rem / 20, r2 = rem % 20, c = r2 / 4, h = r2 % 4;
        wdtb[(h * 128 + 80 + j * 5 + c) * 128 + (80 + i * 5 + c)] = bf16r(Wd2[i * 32 + j * 4 + h] * S_IR2);
    }
}

// ---- node_qkv_v5: fp32 pre-activation (precision-load-bearing — R6 failure).
//      Section-split grid for wave count; per-section output arrays so every
//      thread writes full rows (R9's partial-line WRITE fix). ----

__global__ __launch_bounds__(256) void node_qkv_v5_kernel(
    const float* __restrict__ x, const float* __restrict__ wt,
    ushort_t* __restrict__ S0q, ushort_t* __restrict__ S1q, ushort_t* __restrict__ S2q,
    ushort_t* __restrict__ S0k, ushort_t* __restrict__ S1k, ushort_t* __restrict__ S2k,
    ushort_t* __restrict__ S0v, ushort_t* __restrict__ S1v, ushort_t* __restrict__ S2v,
    int N)
{
    int node = blockIdx.x * 256 + threadIdx.x;
    int p = blockIdx.y;
    int sec = blockIdx.z;
    if (node >= N) return;

    const float4* xp = (const float4*)(x + (size_t)node * FEAT);
    const float* W = wt + p * 1344;

    if (sec == 0) {
        float xs[32];
        #pragma unroll
        for (int i = 0; i < 8; i++) ((float4*)xs)[i] = xp[i];
        uint_t yp[16];
        float prev = 0.0f;
        #pragma unroll
        for (int o = 0; o < 32; o++) {
            float acc = 0.0f;
            const float* w0 = W + o * 32;
            #pragma unroll
            for (int i = 0; i < 32; i++) acc = fmaf(w0[i], xs[i], acc);
            float y = acc * nact_scale(acc * acc);
            if (o & 1) yp[o >> 1] = pack2(prev, y); else prev = y;
        }
        ushort_t* D = (p == 0) ? S0q : (p == 1) ? S0k : S0v;
        uint4* dst = (uint4*)(D + (size_t)node * 32);
        #pragma unroll
        for (int i = 0; i < 4; i++)
            dst[i] = (uint4){yp[4*i], yp[4*i+1], yp[4*i+2], yp[4*i+3]};
    } else if (sec == 1) {
        float xs[48];
        #pragma unroll
        for (int i = 0; i < 12; i++) ((float4*)xs)[i] = xp[8 + i];
        uint_t yp[24];
        float prev = 0.0f;
        #pragma unroll
        for (int o = 0; o < 16; o++) {
            float a0 = 0.0f, a1 = 0.0f, a2 = 0.0f;
            const float* w1 = W + 1024 + o * 16;
            #pragma unroll
            for (int i = 0; i < 16; i++) {
                float w = w1[i];
                a0 = fmaf(w, xs[i * 3 + 0], a0);
                a1 = fmaf(w, xs[i * 3 + 1], a1);
                a2 = fmaf(w, xs[i * 3 + 2], a2);
            }
            float s = nact_scale(a0 * a0 + a1 * a1 + a2 * a2);
            float y0 = a0 * s, y1 = a1 * s, y2 = a2 * s;
            int f = o * 3;
            if (f & 1) {
                yp[f >> 1] = pack2(prev, y0);
                yp[(f >> 1) + 1] = pack2(y1, y2);
            } else {
                yp[f >> 1] = pack2(y0, y1);
                prev = y2;
            }
        }
        ushort_t* D = (p == 0) ? S1q : (p == 1) ? S1k : S1v;
        uint4* dst = (uint4*)(D + (size_t)node * 48);
        #pragma unroll
        for (int i = 0; i < 6; i++)
            dst[i] = (uint4){yp[4*i], yp[4*i+1], yp[4*i+2], yp[4*i+3]};
    } else {
        float xs[40];
        #pragma unroll
        for (int i = 0; i < 10; i++) ((float4*)xs)[i] = xp[20 + i];
        uint_t yp[20];
        float prev = 0.0f;
        #pragma unroll
        for (int o = 0; o < 8; o++) {
            float a0 = 0, a1 = 0, a2 = 0, a3 = 0, a4 = 0;
            const float* w2 = W + 1280 + o * 8;
            #pragma unroll
            for (int i = 0; i < 8; i++) {
                float w = w2[i];
                a0 = fmaf(w, xs[i * 5 + 0], a0);
                a1 = fmaf(w, xs[i * 5 + 1], a1);
                a2 = fmaf(w, xs[i * 5 + 2], a2);
                a3 = fmaf(w, xs[i * 5 + 3], a3);
                a4 = fmaf(w, xs[i * 5 + 4], a4);
            }
            float s = nact_scale(a0*a0 + a1*a1 + a2*a2 + a3*a3 + a4*a4);
            float y0 = a0*s, y1 = a1*s, y2 = a2*s, y3 = a3*s, y4 = a4*s;
            int f = o * 5;
            if (f & 1) {
                yp[f >> 1] = pack2(prev, y0);
                yp[(f >> 1) + 1] = pack2(y1, y2);
                yp[(f >> 1) + 2] = pack2(y3, y4);
            } else {
                yp[f >> 1] = pack2(y0, y1);
                yp[(f >> 1) + 1] = pack2(y2, y3);
                prev = y4;
            }
        }
        ushort_t* D = (p == 0) ? S2q : (p == 1) ? S2k : S2v;
        uint4* dst = (uint4*)(D + (size_t)node * 48);
        #pragma unroll
        for (int i = 0; i < 5; i++)
            dst[i] = (uint4){yp[4*i], yp[4*i+1], yp[4*i+2], yp[4*i+3]};
        dst[5] = (uint4){0, 0, 0, 0};
    }
}

// ---- node_tq_mfma + k/v repack: tqb GEMM from q sections; also repacks the
//      k/v sections into contiguous kb/vb[N][128] rows (the edge kernel's
//      gather locality depends on 2-cache-line rows — R10's 3-array split
//      cost edge +45 µs). ----

__global__ __launch_bounds__(256, 2) void node_tq_mfma_kernel(
    const ushort_t* __restrict__ S0q, const ushort_t* __restrict__ S1q,
    const ushort_t* __restrict__ S2q,
    const ushort_t* __restrict__ S0k, const ushort_t* __restrict__ S1k,
    const ushort_t* __restrict__ S2k,
    const ushort_t* __restrict__ S0v, const ushort_t* __restrict__ S1v,
    const ushort_t* __restrict__ S2v,
    const ushort_t* __restrict__ wdtb,
    ushort_t* __restrict__ tqb, ushort_t* __restrict__ kb, ushort_t* __restrict__ vb,
    int N)
{
    int t = threadIdx.x, lane = t & 63, w = t >> 6;
    int base = blockIdx.x * 16;

    // --- repack: thread t copies chunk c of node rn (16 nodes x 16 chunks) ---
    {
        int rn = t >> 4, c = t & 15;
        int node2 = base + rn;
        if (node2 < N) {
            size_t r32 = (size_t)node2 * 32, r48 = (size_t)node2 * 48;
            uint4 kv, vv;
            if (c < 4)       { kv = *(const uint4*)(S0k + r32 + c * 8);
                               vv = *(const uint4*)(S0v + r32 + c * 8); }
            else if (c < 10) { kv = *(const uint4*)(S1k + r48 + (c - 4) * 8);
                               vv = *(const uint4*)(S1v + r48 + (c - 4) * 8); }
            else             { kv = *(const uint4*)(S2k + r48 + (c - 10) * 8);
                               vv = *(const uint4*)(S2v + r48 + (c - 10) * 8); }
            *(uint4*)(kb + (size_t)node2 * 128 + c * 8) = kv;
            *(uint4*)(vb + (size_t)node2 * 128 + c * 8) = vv;
        }
    }

    // --- tq GEMM (B-frags from q sections) ---
    int nl = lane & 15, quad = lane >> 4, q8 = quad * 8;
    int node = base + nl;
    int nclamp = (node < N) ? node : (N - 1);

    size_t r32 = (size_t)nclamp * 32, r48 = (size_t)nclamp * 48;
    short8 bfr[4];
    bfr[0] = *(const short8*)(S0q + r32 + q8);
    bfr[1] = *(const short8*)(S1q + r48 + q8);
    bfr[2] = (quad < 2) ? *(const short8*)(S1q + r48 + 32 + q8)
                        : *(const short8*)(S2q + r48 + q8 - 16);
    bfr[3] = *(const short8*)(S2q + r48 + 16 + q8);

    #pragma unroll
    for (int ti = 0; ti < 8; ti++) {
        int tile = w * 8 + ti;
        const ushort_t* ap = wdtb + (tile * 16 + nl) * 128 + q8;
        floatx4 C = {0.0f, 0.0f, 0.0f, 0.0f};
        #pragma unroll
        for (int kk = 0; kk < 4; kk++) {
            short8 a = *(const short8*)(ap + kk * 32);
            C = __builtin_amdgcn_mfma_f32_16x16x32_bf16(a, bfr[kk], C, 0, 0, 0);
        }
        if (node < N) {
            uint_t lo = (uint_t)bf16r(C[0]) | ((uint_t)bf16r(C[1]) << 16);
            uint_t hi = (uint_t)bf16r(C[2]) | ((uint_t)bf16r(C[3]) << 16);
            uint_t* dst = (uint_t*)(tqb + (size_t)node * 512 + tile * 16 + quad * 4);
            dst[0] = lo; dst[1] = hi;
        }
    }
}

// ---- edge kernel: contiguous-row gathers (R5-validated), 2-tile unrolled
//      main loop for 2x memory-level parallelism ----

__global__ __launch_bounds__(256) void edge_mfma_kernel(
    const ushort_t* __restrict__ tqb, const ushort_t* __restrict__ kb,
    const ushort_t* __restrict__ vb,
    const int* __restrict__ offsets, const int* __restrict__ ssrc,
    float* __restrict__ out, int N)
{
    int lane = threadIdx.x & 63, wid = threadIdx.x >> 6;
    int node = blockIdx.x * 4 + wid;
    if (node >= N) return;
    node = __builtin_amdgcn_readfirstlane(node);
    int m = lane & 15, quad = lane >> 4, q8 = quad * 8;

    short8 afr[4];
    if (m < HCNT) {
        const short8* ap = (const short8*)(tqb + (size_t)node * 512 + m * 128 + q8);
        #pragma unroll
        for (int b = 0; b < 4; b++) afr[b] = ap[b * 4];
    } else {
        #pragma unroll
        for (int b = 0; b < 4; b++) afr[b] = (short8){0,0,0,0,0,0,0,0};
    }

    int beg = offsets[node], end = offsets[node + 1];
    float zpart = 0.0f, accx = 0.0f, accy = 0.0f;
    const uint_t* vrow = (const uint_t*)vb;

    int p = beg;
    // -------- 2-tile main loop (32 edges/iter) --------
    for (; p + 32 <= end; p += 32) {
        int srcA = ssrc[p + m];
        int srcB = ssrc[p + 16 + m];
        const short8* bpA = (const short8*)(kb + (size_t)srcA * 128 + q8);
        const short8* bpB = (const short8*)(kb + (size_t)srcB * 128 + q8);
        short8 a0 = bpA[0], a1 = bpA[4], a2 = bpA[8], a3 = bpA[12];
        short8 c0 = bpB[0], c1 = bpB[4], c2 = bpB[8], c3 = bpB[12];
        floatx4 CA = {0.0f, 0.0f, 0.0f, 0.0f};
        floatx4 CB = {0.0f, 0.0f, 0.0f, 0.0f};
        CA = __builtin_amdgcn_mfma_f32_16x16x32_bf16(afr[0], a0, CA, 0, 0, 0);
        CB = __builtin_amdgcn_mfma_f32_16x16x32_bf16(afr[0], c0, CB, 0, 0, 0);
        CA = __builtin_amdgcn_mfma_f32_16x16x32_bf16(afr[1], a1, CA, 0, 0, 0);
        CB = __builtin_amdgcn_mfma_f32_16x16x32_bf16(afr[1], c1, CB, 0, 0, 0);
        CA = __builtin_amdgcn_mfma_f32_16x16x32_bf16(afr[2], a2, CA, 0, 0, 0);
        CB = __builtin_amdgcn_mfma_f32_16x16x32_bf16(afr[2], c2, CB, 0, 0, 0);
        CA = __builtin_amdgcn_mfma_f32_16x16x32_bf16(afr[3], a3, CA, 0, 0, 0);
        CB = __builtin_amdgcn_mfma_f32_16x16x32_bf16(afr[3], c3, CB, 0, 0, 0);

        float wA = 0.0f, wB = 0.0f;
        if (quad == 0) {
            float exA = 0.25f * (__expf(CA[0]) + __expf(CA[1]) + __expf(CA[2]) + __expf(CA[3]));
            float exB = 0.25f * (__expf(CB[0]) + __expf(CB[1]) + __expf(CB[2]) + __expf(CB[3]));
            zpart += exA + exB;
            wA = sqrtf(exA); wB = sqrtf(exB);
        }
        #pragma unroll
        for (int half = 0; half < 2; half++) {
            float wsel = half ? wB : wA;
            int ssel = half ? srcB : srcA;
            #pragma unroll
            for (int e0 = 0; e0 < 16; e0 += 8) {
                float we[8]; int se[8]; uint_t vp[8];
                #pragma unroll
                for (int j = 0; j < 8; j++) {
                    we[j] = __shfl(wsel, e0 + j, 64);
                    se[j] = __shfl(ssel, e0 + j, 64);
                }
                #pragma unroll
                for (int j = 0; j < 8; j++) vp[j] = vrow[(size_t)se[j] * 64 + lane];
                #pragma unroll
                for (int j = 0; j < 8; j++) {
                    accx = fmaf(we[j], __uint_as_float(vp[j] << 16), accx);
                    accy = fmaf(we[j], __uint_as_float(vp[j] & 0xffff0000u), accy);
                }
            }
        }
    }
    // -------- single-tile tail --------
    for (; p < end; p += 16) {
        int rem = end - p; if (rem > 16) rem = 16;
        int idx = p + (m < rem ? m : rem - 1);
        int src = ssrc[idx];
        const short8* bp = (const short8*)(kb + (size_t)src * 128 + q8);
        short8 b0 = bp[0], b1 = bp[4], b2 = bp[8], b3 = bp[12];
        floatx4 C = {0.0f, 0.0f, 0.0f, 0.0f};
        C = __builtin_amdgcn_mfma_f32_16x16x32_bf16(afr[0], b0, C, 0, 0, 0);
        C = __builtin_amdgcn_mfma_f32_16x16x32_bf16(afr[1], b1, C, 0, 0, 0);
        C = __builtin_amdgcn_mfma_f32_16x16x32_bf16(afr[2], b2, C, 0, 0, 0);
        C = __builtin_amdgcn_mfma_f32_16x16x32_bf16(afr[3], b3, C, 0, 0, 0);

        float w = 0.0f;
        if (quad == 0 && m < rem) {
            float ex = 0.25f * (__expf(C[0]) + __expf(C[1]) + __expf(C[2]) + __expf(C[3]));
            zpart += ex;
            w = sqrtf(ex);
        }
        for (int e = 0; e < rem; e++) {
            float we = __shfl(w, e, 64);
            int   se = __shfl(src, e, 64);
            uint_t vp = vrow[(size_t)se * 64 + lane];
            accx = fmaf(we, __uint_as_float(vp << 16), accx);
            accy = fmaf(we, __uint_as_float(vp & 0xffff0000u), accy);
        }
    }

    zpart += __shfl_xor(zpart, 1, 64);
    zpart += __shfl_xor(zpart, 2, 64);
    zpart += __shfl_xor(zpart, 4, 64);
    zpart += __shfl_xor(zpart, 8, 64);
    float zsum = __shfl(zpart, 0, 64);
    float scale = (zsum > 0.0f) ? rsqrtf(zsum) : 0.0f;

    if (lane < 60) {
        uint_t vself = vrow[(size_t)node * 64 + lane];
        float2 o;
        o.x = fmaf(accx, scale, __uint_as_float(vself << 16));
        o.y = fmaf(accy, scale, __uint_as_float(vself & 0xffff0000u));
        *((float2*)(out + (size_t)node * FEAT) + lane) = o;
    }
}

// ---------------- launch ----------------

extern "C" void kernel_launch(void* const* d_in, const int* in_sizes, int n_in,
                              void* d_out, int out_size, void* d_ws, size_t ws_size,
                              hipStream_t stream) {
    const float* x   = (const float*)d_in[0];
    const float* Wq0 = (const float*)d_in[1];
    const float* Wq1 = (const float*)d_in[2];
    const float* Wq2 = (const float*)d_in[3];
    const float* Wk0 = (const float*)d_in[4];
    const float* Wk1 = (const float*)d_in[5];
    const float* Wk2 = (const float*)d_in[6];
    const float* Wv0 = (const float*)d_in[7];
    const float* Wv1 = (const float*)d_in[8];
    const float* Wv2 = (const float*)d_in[9];
    const float* Wd0 = (const float*)d_in[10];
    const float* Wd1 = (const float*)d_in[11];
    const float* Wd2 = (const float*)d_in[12];
    const int* edge_dst = (const int*)d_in[13];
    const int* edge_src = (const int*)d_in[14];
    float* out = (float*)d_out;

    int N = in_sizes[0] / FEAT;
    int E = in_sizes[13];

    ushort_t* S0q = (ushort_t*)d_ws;                  // N*32
    ushort_t* S1q = S0q + (size_t)N * 32;             // N*48
    ushort_t* S2q = S1q + (size_t)N * 48;             // N*48
    ushort_t* S0k = S2q + (size_t)N * 48;             // N*32
    ushort_t* S1k = S0k + (size_t)N * 32;             // N*48
    ushort_t* S2k = S1k + (size_t)N * 48;             // N*48
    ushort_t* S0v = S2k + (size_t)N * 48;             // N*32
    ushort_t* S1v = S0v + (size_t)N * 32;             // N*48
    ushort_t* S2v = S1v + (size_t)N * 48;             // N*48
    ushort_t* kb  = S2v + (size_t)N * 48;             // N*128
    ushort_t* vb  = kb + (size_t)N * 128;             // N*128
    ushort_t* tqb = vb + (size_t)N * 128;             // N*512
    ushort_t* wdtb = tqb + (size_t)N * 512;           // 512*128 bf16
    float* wt      = (float*)(wdtb + 65536);          // 3*1344 fp32
    int* offsets = (int*)(wt + 4032);                 // N+1
    int* cursor  = offsets + (N + 1);                 // N
    int* bsum    = cursor + N;                        // 256
    int* ssrc    = bsum + 256;                        // E

    int NB = (N + 255) / 256;
    int EB = (E + 255) / 256;
    int NW = (N + 3) / 4;
    int NT = (N + 15) / 16;

    prep_fill_kernel<<<1, 256, 0, stream>>>(Wq0, Wq1, Wq2, Wk0, Wk1, Wk2,
                                            Wv0, Wv1, Wv2, Wd0, Wd1, Wd2, wt, wdtb);

    hipMemsetAsync(cursor, 0, (size_t)N * sizeof(int), stream);
    hist_kernel<<<EB, 256, 0, stream>>>(edge_dst, cursor, E);
    scan_block_kernel<<<NB, 256, 0, stream>>>(cursor, offsets, bsum, N);
    scan_sums_kernel<<<1, 256, 0, stream>>>(bsum, NB);
    add_offsets_kernel<<<NB, 256, 0, stream>>>(offsets, bsum, cursor, N, E);
    scatter_kernel<<<EB, 256, 0, stream>>>(edge_dst, edge_src, cursor, ssrc, E);

    node_qkv_v5_kernel<<<dim3(NB, 3, 3), 256, 0, stream>>>(
        x, wt, S0q, S1q, S2q, S0k, S1k, S2k, S0v, S1v, S2v, N);
    node_tq_mfma_kernel<<<NT, 256, 0, stream>>>(S0q, S1q, S2q, S0k, S1k, S2k,
                                                S0v, S1v, S2v, wdtb, tqb, kb, vb, N);
    edge_mfma_kernel<<<NW, 256, 0, stream>>>(tqb, kb, vb, offsets, ssrc, out, N);
}

// Round 12
// 379.235 us; speedup vs baseline: 1.1418x; 1.1418x over previous
//
#include <hip/hip_runtime.h>
#include <math.h>

#define FEAT 120
#define HCNT 4

typedef unsigned short ushort_t;
typedef unsigned int uint_t;
typedef __attribute__((ext_vector_type(8))) short short8;
typedef __attribute__((ext_vector_type(4))) float floatx4;

__device__ __forceinline__ float nact_scale(float sumsq) {
    float n = sqrtf(sumsq + 1e-10f);
    float sig = 1.0f / (1.0f + expf(-n));
    return sig / n;
}

__device__ __forceinline__ ushort_t bf16r(float f) {
    uint_t u = __float_as_uint(f);
    u += 0x7fff + ((u >> 16) & 1);   // round-to-nearest-even
    return (ushort_t)(u >> 16);
}

__device__ __forceinline__ uint_t pack2(float lo, float hi) {
    return (uint_t)bf16r(lo) | ((uint_t)bf16r(hi) << 16);
}

#define INV_S32 0.17677669529663687f   // 1/sqrt(32)
#define INV_S16 0.25f                  // 1/sqrt(16)
#define INV_S8  0.35355339059327373f   // 1/sqrt(8)
// tp_dot scales: 1/(sqrt(2l+1)*sqrt(fan)), fan = 32*32 + 16*16*3 + 8*8*5 = 2112
#define S_IR0 0.02175970668223486f
#define S_IR1 0.012562972567021898f
#define S_IR2 0.009731317442393031f

// ---------------- counting sort by dst ----------------

__global__ __launch_bounds__(256) void hist_kernel(const int* __restrict__ dst,
                                                   int* __restrict__ cnt, int E) {
    int e = blockIdx.x * 256 + threadIdx.x;
    if (e < E) atomicAdd(&cnt[dst[e]], 1);
}

__global__ __launch_bounds__(256) void scan_block_kernel(const int* __restrict__ cnt,
                                                         int* __restrict__ excl,
                                                         int* __restrict__ bsum, int n) {
    __shared__ int s[256];
    int t = threadIdx.x;
    int i = blockIdx.x * 256 + t;
    int v = (i < n) ? cnt[i] : 0;
    s[t] = v;
    __syncthreads();
    for (int off = 1; off < 256; off <<= 1) {
        int add = (t >= off) ? s[t - off] : 0;
        __syncthreads();
        s[t] += add;
        __syncthreads();
    }
    if (i < n) excl[i] = s[t] - v;
    if (t == 255) bsum[blockIdx.x] = s[255];
}

__global__ __launch_bounds__(256) void scan_sums_kernel(int* __restrict__ bsum, int nb) {
    __shared__ int s[256];
    int t = threadIdx.x;
    int v = (t < nb) ? bsum[t] : 0;
    s[t] = v;
    __syncthreads();
    for (int off = 1; off < 256; off <<= 1) {
        int add = (t >= off) ? s[t - off] : 0;
        __syncthreads();
        s[t] += add;
        __syncthreads();
    }
    if (t < nb) bsum[t] = s[t] - v;
}

__global__ __launch_bounds__(256) void add_offsets_kernel(int* __restrict__ offsets,
                                                          const int* __restrict__ bsum,
                                                          int* __restrict__ cursor,
                                                          int n, int E) {
    int i = blockIdx.x * 256 + threadIdx.x;
    if (i < n) {
        int off = offsets[i] + bsum[i >> 8];
        offsets[i] = off;
        cursor[i] = off;
    }
    if (i == 0) offsets[n] = E;
}

__global__ __launch_bounds__(256) void scatter_kernel(const int* __restrict__ dst,
                                                      const int* __restrict__ src,
                                                      int* __restrict__ cursor,
                                                      int* __restrict__ ssrc, int E) {
    int e = blockIdx.x * 256 + threadIdx.x;
    if (e < E) {
        int pos = atomicAdd(&cursor[dst[e]], 1);
        ssrc[pos] = src[e];
    }
}

// ---------------- weight prep (zero + fill fused, one block) ----------------

__global__ __launch_bounds__(256) void prep_fill_kernel(
    const float* __restrict__ Wq0, const float* __restrict__ Wq1, const float* __restrict__ Wq2,
    const float* __restrict__ Wk0, const float* __restrict__ Wk1, const float* __restrict__ Wk2,
    const float* __restrict__ Wv0, const float* __restrict__ Wv1, const float* __restrict__ Wv2,
    const float* __restrict__ Wd0, const float* __restrict__ Wd1, const float* __restrict__ Wd2,
    float* __restrict__ wt, ushort_t* __restrict__ wdtb)
{
    int t = threadIdx.x;
    for (int it = t; it < 32768; it += 256) ((uint_t*)wdtb)[it] = 0;
    __syncthreads();
    for (int it = t; it < 3072; it += 256) {
        int p = it >> 10, rem = it & 1023, o = rem >> 5, i = rem & 31;
        const float* W = (p == 0) ? Wq0 : (p == 1) ? Wk0 : Wv0;
        wt[p * 1344 + o * 32 + i] = W[i * 32 + o] * INV_S32;
    }
    for (int it = t; it < 768; it += 256) {
        int p = it >> 8, rem = it & 255, o = rem >> 4, i = rem & 15;
        const float* W = (p == 0) ? Wq1 : (p == 1) ? Wk1 : Wv1;
        wt[p * 1344 + 1024 + o * 16 + i] = W[i * 16 + o] * INV_S16;
    }
    for (int it = t; it < 192; it += 256) {
        int p = it / 64, rem = it % 64, o = rem >> 3, i = rem & 7;
        const float* W = (p == 0) ? Wq2 : (p == 1) ? Wk2 : Wv2;
        wt[p * 1344 + 1280 + o * 8 + i] = W[i * 8 + o] * INV_S8;
    }
    // wd l=0: Wd0 (32,32,4): Wd0[i][j][h] = Wd0[i*128 + j*4 + h]
    for (int it = t; it < 4096; it += 256) {
        int i = it / 128, rem = it % 128, j = rem / 4, h = rem % 4;
        wdtb[(h * 128 + j) * 128 + i] = bf16r(Wd0[i * 128 + j * 4 + h] * S_IR0);
    }
    // wd l=1: Wd1 (16,16,4)
    for (int it = t; it < 3072; it += 256) {
        int i = it / 192, rem = it % 192, j = rem / 12, r2 = rem % 12, c = r2 / 4, h = r2 % 4;
        wdtb[(h * 128 + 32 + j * 3 + c) * 128 + (32 + i * 3 + c)] = bf16r(Wd1[i * 64 + j * 4 + h] * S_IR1);
    }
    // wd l=2: Wd2 (8,8,4)
    for (int it = t; it < 1280; it += 256) {
        int i = it / 160, rem = it % 160, j = rem / 20, r2 = rem % 20, c = r2 / 4, h = r2 % 4;
        wdtb[(h * 128 + 80 + j * 5 + c) * 128 + (80 + i * 5 + c)] = bf16r(Wd2[i * 32 + j * 4 + h] * S_IR2);
    }
}

// ---- node_qkv_v5: fp32 pre-activation (precision-load-bearing — R6 failure).
//      Section-split grid for wave count; per-section output arrays so every
//      thread writes full rows (R9's partial-line WRITE fix). ----

__global__ __launch_bounds__(256) void node_qkv_v5_kernel(
    const float* __restrict__ x, const float* __restrict__ wt,
    ushort_t* __restrict__ S0q, ushort_t* __restrict__ S1q, ushort_t* __restrict__ S2q,
    ushort_t* __restrict__ S0k, ushort_t* __restrict__ S1k, ushort_t* __restrict__ S2k,
    ushort_t* __restrict__ S0v, ushort_t* __restrict__ S1v, ushort_t* __restrict__ S2v,
    int N)
{
    int node = blockIdx.x * 256 + threadIdx.x;
    int p = blockIdx.y;
    int sec = blockIdx.z;
    if (node >= N) return;

    const float4* xp = (const float4*)(x + (size_t)node * FEAT);
    const float* W = wt + p * 1344;

    if (sec == 0) {
        float xs[32];
        #pragma unroll
        for (int i = 0; i < 8; i++) ((float4*)xs)[i] = xp[i];
        uint_t yp[16];
        float prev = 0.0f;
        #pragma unroll
        for (int o = 0; o < 32; o++) {
            float acc = 0.0f;
            const float* w0 = W + o * 32;
            #pragma unroll
            for (int i = 0; i < 32; i++) acc = fmaf(w0[i], xs[i], acc);
            float y = acc * nact_scale(acc * acc);
            if (o & 1) yp[o >> 1] = pack2(prev, y); else prev = y;
        }
        ushort_t* D = (p == 0) ? S0q : (p == 1) ? S0k : S0v;
        uint4* dst = (uint4*)(D + (size_t)node * 32);
        #pragma unroll
        for (int i = 0; i < 4; i++)
            dst[i] = (uint4){yp[4*i], yp[4*i+1], yp[4*i+2], yp[4*i+3]};
    } else if (sec == 1) {
        float xs[48];
        #pragma unroll
        for (int i = 0; i < 12; i++) ((float4*)xs)[i] = xp[8 + i];
        uint_t yp[24];
        float prev = 0.0f;
        #pragma unroll
        for (int o = 0; o < 16; o++) {
            float a0 = 0.0f, a1 = 0.0f, a2 = 0.0f;
            const float* w1 = W + 1024 + o * 16;
            #pragma unroll
            for (int i = 0; i < 16; i++) {
                float w = w1[i];
                a0 = fmaf(w, xs[i * 3 + 0], a0);
                a1 = fmaf(w, xs[i * 3 + 1], a1);
                a2 = fmaf(w, xs[i * 3 + 2], a2);
            }
            float s = nact_scale(a0 * a0 + a1 * a1 + a2 * a2);
            float y0 = a0 * s, y1 = a1 * s, y2 = a2 * s;
            int f = o * 3;
            if (f & 1) {
                yp[f >> 1] = pack2(prev, y0);
                yp[(f >> 1) + 1] = pack2(y1, y2);
            } else {
                yp[f >> 1] = pack2(y0, y1);
                prev = y2;
            }
        }
        ushort_t* D = (p == 0) ? S1q : (p == 1) ? S1k : S1v;
        uint4* dst = (uint4*)(D + (size_t)node * 48);
        #pragma unroll
        for (int i = 0; i < 6; i++)
            dst[i] = (uint4){yp[4*i], yp[4*i+1], yp[4*i+2], yp[4*i+3]};
    } else {
        float xs[40];
        #pragma unroll
        for (int i = 0; i < 10; i++) ((float4*)xs)[i] = xp[20 + i];
        uint_t yp[20];
        float prev = 0.0f;
        #pragma unroll
        for (int o = 0; o < 8; o++) {
            float a0 = 0, a1 = 0, a2 = 0, a3 = 0, a4 = 0;
            const float* w2 = W + 1280 + o * 8;
            #pragma unroll
            for (int i = 0; i < 8; i++) {
                float w = w2[i];
                a0 = fmaf(w, xs[i * 5 + 0], a0);
                a1 = fmaf(w, xs[i * 5 + 1], a1);
                a2 = fmaf(w, xs[i * 5 + 2], a2);
                a3 = fmaf(w, xs[i * 5 + 3], a3);
                a4 = fmaf(w, xs[i * 5 + 4], a4);
            }
            float s = nact_scale(a0*a0 + a1*a1 + a2*a2 + a3*a3 + a4*a4);
            float y0 = a0*s, y1 = a1*s, y2 = a2*s, y3 = a3*s, y4 = a4*s;
            int f = o * 5;
            if (f & 1) {
                yp[f >> 1] = pack2(prev, y0);
                yp[(f >> 1) + 1] = pack2(y1, y2);
                yp[(f >> 1) + 2] = pack2(y3, y4);
            } else {
                yp[f >> 1] = pack2(y0, y1);
                yp[(f >> 1) + 1] = pack2(y2, y3);
                prev = y4;
            }
        }
        ushort_t* D = (p == 0) ? S2q : (p == 1) ? S2k : S2v;
        uint4* dst = (uint4*)(D + (size_t)node * 48);
        #pragma unroll
        for (int i = 0; i < 5; i++)
            dst[i] = (uint4){yp[4*i], yp[4*i+1], yp[4*i+2], yp[4*i+3]};
        dst[5] = (uint4){0, 0, 0, 0};
    }
}

// ---- node_tq_mfma + k/v repack into contiguous kb/vb[N][128] (edge gather
//      locality needs 2-line rows — R10 lesson; repack confirmed by R11's
//      FETCH halving 375->208 MB) ----

__global__ __launch_bounds__(256, 2) void node_tq_mfma_kernel(
    const ushort_t* __restrict__ S0q, const ushort_t* __restrict__ S1q,
    const ushort_t* __restrict__ S2q,
    const ushort_t* __restrict__ S0k, const ushort_t* __restrict__ S1k,
    const ushort_t* __restrict__ S2k,
    const ushort_t* __restrict__ S0v, const ushort_t* __restrict__ S1v,
    const ushort_t* __restrict__ S2v,
    const ushort_t* __restrict__ wdtb,
    ushort_t* __restrict__ tqb, ushort_t* __restrict__ kb, ushort_t* __restrict__ vb,
    int N)
{
    int t = threadIdx.x, lane = t & 63, w = t >> 6;
    int base = blockIdx.x * 16;

    // --- repack: thread t copies chunk c of node rn (16 nodes x 16 chunks) ---
    {
        int rn = t >> 4, c = t & 15;
        int node2 = base + rn;
        if (node2 < N) {
            size_t r32 = (size_t)node2 * 32, r48 = (size_t)node2 * 48;
            uint4 kv, vv;
            if (c < 4)       { kv = *(const uint4*)(S0k + r32 + c * 8);
                               vv = *(const uint4*)(S0v + r32 + c * 8); }
            else if (c < 10) { kv = *(const uint4*)(S1k + r48 + (c - 4) * 8);
                               vv = *(const uint4*)(S1v + r48 + (c - 4) * 8); }
            else             { kv = *(const uint4*)(S2k + r48 + (c - 10) * 8);
                               vv = *(const uint4*)(S2v + r48 + (c - 10) * 8); }
            *(uint4*)(kb + (size_t)node2 * 128 + c * 8) = kv;
            *(uint4*)(vb + (size_t)node2 * 128 + c * 8) = vv;
        }
    }

    // --- tq GEMM (B-frags from q sections) ---
    int nl = lane & 15, quad = lane >> 4, q8 = quad * 8;
    int node = base + nl;
    int nclamp = (node < N) ? node : (N - 1);

    size_t r32 = (size_t)nclamp * 32, r48 = (size_t)nclamp * 48;
    short8 bfr[4];
    bfr[0] = *(const short8*)(S0q + r32 + q8);
    bfr[1] = *(const short8*)(S1q + r48 + q8);
    bfr[2] = (quad < 2) ? *(const short8*)(S1q + r48 + 32 + q8)
                        : *(const short8*)(S2q + r48 + q8 - 16);
    bfr[3] = *(const short8*)(S2q + r48 + 16 + q8);

    #pragma unroll
    for (int ti = 0; ti < 8; ti++) {
        int tile = w * 8 + ti;
        const ushort_t* ap = wdtb + (tile * 16 + nl) * 128 + q8;
        floatx4 C = {0.0f, 0.0f, 0.0f, 0.0f};
        #pragma unroll
        for (int kk = 0; kk < 4; kk++) {
            short8 a = *(const short8*)(ap + kk * 32);
            C = __builtin_amdgcn_mfma_f32_16x16x32_bf16(a, bfr[kk], C, 0, 0, 0);
        }
        if (node < N) {
            uint_t lo = (uint_t)bf16r(C[0]) | ((uint_t)bf16r(C[1]) << 16);
            uint_t hi = (uint_t)bf16r(C[2]) | ((uint_t)bf16r(C[3]) << 16);
            uint_t* dst = (uint_t*)(tqb + (size_t)node * 512 + tile * 16 + quad * 4);
            dst[0] = lo; dst[1] = hi;
        }
    }
}

// ---- edge kernel: R5/R8-proven single-tile loop (mean degree = 16 ->
//      one tile per node typical; R11's 2-tile unroll never ran and its
//      VGPR cost cut occupancy 47->35%). Contiguous kb/vb rows. ----

__global__ __launch_bounds__(256) void edge_mfma_kernel(
    const ushort_t* __restrict__ tqb, const ushort_t* __restrict__ kb,
    const ushort_t* __restrict__ vb,
    const int* __restrict__ offsets, const int* __restrict__ ssrc,
    float* __restrict__ out, int N)
{
    int lane = threadIdx.x & 63, wid = threadIdx.x >> 6;
    int node = blockIdx.x * 4 + wid;
    if (node >= N) return;
    node = __builtin_amdgcn_readfirstlane(node);
    int m = lane & 15, quad = lane >> 4;

    short8 afr[4];
    if (m < HCNT) {
        const short8* ap = (const short8*)(tqb + (size_t)node * 512 + m * 128 + quad * 8);
        #pragma unroll
        for (int b = 0; b < 4; b++) afr[b] = ap[b * 4];
    } else {
        #pragma unroll
        for (int b = 0; b < 4; b++) afr[b] = (short8){0,0,0,0,0,0,0,0};
    }

    int beg = offsets[node], end = offsets[node + 1];
    float zpart = 0.0f, accx = 0.0f, accy = 0.0f;
    const uint_t* vrow = (const uint_t*)vb;

    for (int tb = beg; tb < end; tb += 16) {
        int rem = end - tb; if (rem > 16) rem = 16;
        int idx = tb + (m < rem ? m : rem - 1);
        int src = ssrc[idx];
        const short8* bp = (const short8*)(kb + (size_t)src * 128 + quad * 8);
        short8 b0 = bp[0], b1 = bp[4], b2 = bp[8], b3 = bp[12];
        floatx4 C = {0.0f, 0.0f, 0.0f, 0.0f};
        C = __builtin_amdgcn_mfma_f32_16x16x32_bf16(afr[0], b0, C, 0, 0, 0);
        C = __builtin_amdgcn_mfma_f32_16x16x32_bf16(afr[1], b1, C, 0, 0, 0);
        C = __builtin_amdgcn_mfma_f32_16x16x32_bf16(afr[2], b2, C, 0, 0, 0);
        C = __builtin_amdgcn_mfma_f32_16x16x32_bf16(afr[3], b3, C, 0, 0, 0);

        float w = 0.0f;
        if (quad == 0 && m < rem) {
            float ex = 0.25f * (__expf(C[0]) + __expf(C[1]) + __expf(C[2]) + __expf(C[3]));
            zpart += ex;
            w = sqrtf(ex);
        }

        if (rem == 16) {
            #pragma unroll
            for (int e0 = 0; e0 < 16; e0 += 8) {
                float we[8]; int se[8]; uint_t vp[8];
                #pragma unroll
                for (int j = 0; j < 8; j++) {
                    we[j] = __shfl(w, e0 + j, 64);
                    se[j] = __shfl(src, e0 + j, 64);
                }
                #pragma unroll
                for (int j = 0; j < 8; j++) vp[j] = vrow[(size_t)se[j] * 64 + lane];
                #pragma unroll
                for (int j = 0; j < 8; j++) {
                    accx = fmaf(we[j], __uint_as_float(vp[j] << 16), accx);
                    accy = fmaf(we[j], __uint_as_float(vp[j] & 0xffff0000u), accy);
                }
            }
        } else {
            for (int e = 0; e < rem; e++) {
                float we = __shfl(w, e, 64);
                int   se = __shfl(src, e, 64);
                uint_t vp = vrow[(size_t)se * 64 + lane];
                accx = fmaf(we, __uint_as_float(vp << 16), accx);
                accy = fmaf(we, __uint_as_float(vp & 0xffff0000u), accy);
            }
        }
    }

    zpart += __shfl_xor(zpart, 1, 64);
    zpart += __shfl_xor(zpart, 2, 64);
    zpart += __shfl_xor(zpart, 4, 64);
    zpart += __shfl_xor(zpart, 8, 64);
    float zsum = __shfl(zpart, 0, 64);
    float scale = (zsum > 0.0f) ? rsqrtf(zsum) : 0.0f;

    if (lane < 60) {
        uint_t vself = vrow[(size_t)node * 64 + lane];
        float2 o;
        o.x = fmaf(accx, scale, __uint_as_float(vself << 16));
        o.y = fmaf(accy, scale, __uint_as_float(vself & 0xffff0000u));
        *((float2*)(out + (size_t)node * FEAT) + lane) = o;
    }
}

// ---------------- launch ----------------

extern "C" void kernel_launch(void* const* d_in, const int* in_sizes, int n_in,
                              void* d_out, int out_size, void* d_ws, size_t ws_size,
                              hipStream_t stream) {
    const float* x   = (const float*)d_in[0];
    const float* Wq0 = (const float*)d_in[1];
    const float* Wq1 = (const float*)d_in[2];
    const float* Wq2 = (const float*)d_in[3];
    const float* Wk0 = (const float*)d_in[4];
    const float* Wk1 = (const float*)d_in[5];
    const float* Wk2 = (const float*)d_in[6];
    const float* Wv0 = (const float*)d_in[7];
    const float* Wv1 = (const float*)d_in[8];
    const float* Wv2 = (const float*)d_in[9];
    const float* Wd0 = (const float*)d_in[10];
    const float* Wd1 = (const float*)d_in[11];
    const float* Wd2 = (const float*)d_in[12];
    const int* edge_dst = (const int*)d_in[13];
    const int* edge_src = (const int*)d_in[14];
    float* out = (float*)d_out;

    int N = in_sizes[0] / FEAT;
    int E = in_sizes[13];

    ushort_t* S0q = (ushort_t*)d_ws;                  // N*32
    ushort_t* S1q = S0q + (size_t)N * 32;             // N*48
    ushort_t* S2q = S1q + (size_t)N * 48;             // N*48
    ushort_t* S0k = S2q + (size_t)N * 48;             // N*32
    ushort_t* S1k = S0k + (size_t)N * 32;             // N*48
    ushort_t* S2k = S1k + (size_t)N * 48;             // N*48
    ushort_t* S0v = S2k + (size_t)N * 48;             // N*32
    ushort_t* S1v = S0v + (size_t)N * 32;             // N*48
    ushort_t* S2v = S1v + (size_t)N * 48;             // N*48
    ushort_t* kb  = S2v + (size_t)N * 48;             // N*128
    ushort_t* vb  = kb + (size_t)N * 128;             // N*128
    ushort_t* tqb = vb + (size_t)N * 128;             // N*512
    ushort_t* wdtb = tqb + (size_t)N * 512;           // 512*128 bf16
    float* wt      = (float*)(wdtb + 65536);          // 3*1344 fp32
    int* offsets = (int*)(wt + 4032);                 // N+1
    int* cursor  = offsets + (N + 1);                 // N
    int* bsum    = cursor + N;                        // 256
    int* ssrc    = bsum + 256;                        // E

    int NB = (N + 255) / 256;
    int EB = (E + 255) / 256;
    int NW = (N + 3) / 4;
    int NT = (N + 15) / 16;

    prep_fill_kernel<<<1, 256, 0, stream>>>(Wq0, Wq1, Wq2, Wk0, Wk1, Wk2,
                                            Wv0, Wv1, Wv2, Wd0, Wd1, Wd2, wt, wdtb);

    hipMemsetAsync(cursor, 0, (size_t)N * sizeof(int), stream);
    hist_kernel<<<EB, 256, 0, stream>>>(edge_dst, cursor, E);
    scan_block_kernel<<<NB, 256, 0, stream>>>(cursor, offsets, bsum, N);
    scan_sums_kernel<<<1, 256, 0, stream>>>(bsum, NB);
    add_offsets_kernel<<<NB, 256, 0, stream>>>(offsets, bsum, cursor, N, E);
    scatter_kernel<<<EB, 256, 0, stream>>>(edge_dst, edge_src, cursor, ssrc, E);

    node_qkv_v5_kernel<<<dim3(NB, 3, 3), 256, 0, stream>>>(
        x, wt, S0q, S1q, S2q, S0k, S1k, S2k, S0v, S1v, S2v, N);
    node_tq_mfma_kernel<<<NT, 256, 0, stream>>>(S0q, S1q, S2q, S0k, S1k, S2k,
                                                S0v, S1v, S2v, wdtb, tqb, kb, vb, N);
    edge_mfma_kernel<<<NW, 256, 0, stream>>>(tqb, kb, vb, offsets, ssrc, out, N);
}